// Round 5
// baseline (102.858 us; speedup 1.0000x reference)
//
#include <hip/hip_runtime.h>
#include <math.h>

#define NTH 1024                    // 16 waves per block, 2 blocks/CU = 32 waves/CU (full)
#define KP 264                      // LDS row stride (ushorts), padded
#define SPB 16                      // samples per block (fills M=16 MFMA tiles)
#define OFF_W2 0                    // 4 tiles x 4 ksteps
#define OFF_V1 16384                // 16 x 2
#define OFF_V2 49152                // 16 x 8
#define OFF_V3 180224               // 4 x 8
#define WS_USHORTS 212992
#define MFMA16 __builtin_amdgcn_mfma_f32_16x16x32_bf16

typedef __attribute__((ext_vector_type(8))) short s16x8;
typedef __attribute__((ext_vector_type(8))) unsigned short u16x8;
typedef __attribute__((ext_vector_type(4))) float f32x4;

//=============== DPP wave reductions (VALU pipe, no DS traffic) ===============
// row_shr:1/2/4/8 then row_bcast15/row_bcast31 -> lane63 holds the full
// reduction; readlane(63) broadcasts via SGPR. Max is exact (associative);
// sum order differs from the old shfl_xor butterfly by ~1ulp rounding only.
__device__ __forceinline__ float dppRedMax(float v) {
#define MSTEP(ctrl)                                                            \
  v = fmaxf(v, __int_as_float(__builtin_amdgcn_update_dpp(                     \
          (int)0xFF800000u, __float_as_int(v), ctrl, 0xF, 0xF, false)))
  MSTEP(0x111); MSTEP(0x112); MSTEP(0x114); MSTEP(0x118);
  MSTEP(0x142); MSTEP(0x143);
#undef MSTEP
  return __int_as_float(__builtin_amdgcn_readlane(__float_as_int(v), 63));
}

__device__ __forceinline__ float dppRedSum(float v) {
#define SSTEP(ctrl)                                                            \
  v = v + __int_as_float(__builtin_amdgcn_update_dpp(                          \
          0, __float_as_int(v), ctrl, 0xF, 0xF, false))
  SSTEP(0x111); SSTEP(0x112); SSTEP(0x114); SSTEP(0x118);
  SSTEP(0x142); SSTEP(0x143);
#undef SSTEP
  return __int_as_float(__builtin_amdgcn_readlane(__float_as_int(v), 63));
}

// Old shfl-based reductions kept for the fallback kernel only.
__device__ __forceinline__ float waveSum(float v) {
#pragma unroll
  for (int off = 32; off; off >>= 1) v += __shfl_xor(v, off, 64);
  return v;
}

// Fast silu: __expf error ~1e-7 rel; output is bf16-rounded (2^-9) anyway.
__device__ __forceinline__ float siluf(float x) { return x / (1.0f + __expf(-x)); }

// Round fp32 -> bf16 (RNE), return bits.
__device__ __forceinline__ unsigned short bround(float x) {
  unsigned u = __float_as_uint(x);
  return (unsigned short)((u + 0x7FFFu + ((u >> 16) & 1u)) >> 16);
}

// Split fp32 into bf16 hi + bf16 lo (round-to-nearest-even).
__device__ __forceinline__ void bsplit(float x, unsigned short& h, unsigned short& l) {
  unsigned u = __float_as_uint(x);
  unsigned hb = (u + 0x7FFFu + ((u >> 16) & 1u)) >> 16;
  float hf = __uint_as_float(hb << 16);
  float lf = x - hf;
  unsigned ul = __float_as_uint(lf);
  unsigned lb = (ul + 0x7FFFu + ((ul >> 16) & 1u)) >> 16;
  h = (unsigned short)hb; l = (unsigned short)lb;
}

//========= Register perm codes: each lane needs only p=lane, p=lane+64 =========
// Identical factorial decode as before -> bit-exact digit order.
__device__ __forceinline__ unsigned permCode(int p) {
  int rem = p;
  unsigned avail = 0x43210u, code = 0;
#pragma unroll
  for (int j = 0; j < 4; ++j) {
    const int fct = (j == 0) ? 24 : (j == 1) ? 6 : (j == 2) ? 2 : 1;
    int q = rem / fct; rem -= q * fct;
    int sh = q * 4;
    unsigned dg = (avail >> sh) & 0xF;
    avail = (avail & ((1u << sh) - 1u)) | ((avail >> (sh + 4)) << sh);
    code |= dg << (3 * j);
  }
  return code;
}

__device__ __forceinline__ float permTerm(unsigned code, float se0, float se1,
                                          float se2, float se3, float se4,
                                          float Z) {
  float c = 0.0f, prod = Z;
#pragma unroll
  for (int j = 0; j < 4; ++j) {
    int dg = (code >> (3 * j)) & 7;
    float ev = (dg == 0) ? se0 : (dg == 1) ? se1 : (dg == 2) ? se2
             : (dg == 3) ? se3 : se4;
    c += ev;
    prod *= (Z - c);
  }
  return __builtin_amdgcn_rcpf(prod);
}

// One argmax extraction: DPP max (exact) -> ballot (ties -> lowest lane,
// matching jax.lax.top_k) -> readlane broadcast of (ev, lv); winner masked.
__device__ __forceinline__ int extractMax(float& vv, float ev, float lv,
                                          int lane, float& seo, float& lvo) {
  float m = dppRedMax(vv);
  unsigned long long bm = __ballot(vv == m);
  int j = __ffsll(bm) - 1;
  seo = __uint_as_float(__builtin_amdgcn_readlane(__float_as_uint(ev), j));
  lvo = __uint_as_float(__builtin_amdgcn_readlane(__float_as_uint(lv), j));
  vv = (lane == j) ? -INFINITY : vv;
  return j;
}

// Register-based Gumbel top-5 + exact PL log-prob. Extraction order == rank
// order; per-lane psum term order identical to the original pp=0,1 loop.
__device__ __forceinline__ float selectPL5(float lv, float ev, float Z, float g,
                                           float* __restrict__ gout, int lane,
                                           unsigned code0, unsigned code1,
                                           int* __restrict__ jr /*int[5] or null*/) {
  float vv = lv + g;
  unsigned long long sb = 0;
  float se0, se1, se2, se3, se4, l0, l1, l2, l3, l4;
  int j;
  j = extractMax(vv, ev, lv, lane, se0, l0); sb |= 1ull << j; if (jr) jr[0] = j;
  j = extractMax(vv, ev, lv, lane, se1, l1); sb |= 1ull << j; if (jr) jr[1] = j;
  j = extractMax(vv, ev, lv, lane, se2, l2); sb |= 1ull << j; if (jr) jr[2] = j;
  j = extractMax(vv, ev, lv, lane, se3, l3); sb |= 1ull << j; if (jr) jr[3] = j;
  j = extractMax(vv, ev, lv, lane, se4, l4); sb |= 1ull << j; if (jr) jr[4] = j;
  gout[lane] = (float)((sb >> lane) & 1ull);
  float sl = (((l0 + l1) + l2) + l3) + l4;   // left-assoc, rank order (as before)
  float psum = permTerm(code0, se0, se1, se2, se3, se4, Z);       // p = lane
  if (lane < 56)
    psum += permTerm(code1, se0, se1, se2, se3, se4, Z);          // p = lane+64
  float S = dppRedSum(psum);
  return sl + __logf(S);
}

//============ Prep: tile + split weights into fragment order ============
__global__ __launch_bounds__(256)
void pcf_prep(const float* __restrict__ W2, const float* __restrict__ V1,
              const float* __restrict__ V2, const float* __restrict__ V3,
              unsigned short* __restrict__ ws)
{
  int tid = blockIdx.x * 256 + threadIdx.x;
  const float* src; int N, Ks, dstoff, r;
  if (tid < 1024)       { src = W2;            N = 64;  Ks = 4; dstoff = OFF_W2; r = tid; }
  else if (tid < 3072)  { src = V1 + 64 * 256; N = 256; Ks = 2; dstoff = OFF_V1; r = tid - 1024; }
  else if (tid < 11264) { src = V2;            N = 256; Ks = 8; dstoff = OFF_V2; r = tid - 3072; }
  else                  { src = V3;            N = 64;  Ks = 8; dstoff = OFF_V3; r = tid - 11264; }
  int lane = r & 63, ts = r >> 6;
  int ks = ts % Ks, ct = ts / Ks;
  int n = ct * 16 + (lane & 15);
  int k0 = ks * 32 + (lane >> 4) * 8;
  u16x8 hv, lv;
#pragma unroll
  for (int j = 0; j < 8; ++j) {
    float x = src[(size_t)(k0 + j) * N + n];
    unsigned short h, l;
    bsplit(x, h, l);
    hv[j] = h; lv[j] = l;
  }
  unsigned short* dst = ws + dstoff + (size_t)ts * 1024 + lane * 8;
  *(u16x8*)dst = hv;
  *(u16x8*)(dst + 512) = lv;
}

//============ Main: 16 samples/block, 16 waves, MFMA (act hi, wt hi+lo) =====
// R5: DPP-based wave reductions (no DS shuffles), register perm codes (no
// sPerm LDS + one barrier fewer), R4 prefetch pipeline retained.
__global__ __launch_bounds__(NTH, 8)
void pcf_mfma(const float* __restrict__ ua, const float* __restrict__ ub,
              const float* __restrict__ alog, const float* __restrict__ W1,
              const float* __restrict__ b1, const float* __restrict__ b2,
              const float* __restrict__ c1, const float* __restrict__ c2,
              const float* __restrict__ c3,
              const unsigned short* __restrict__ wt, float* __restrict__ out)
{
  __shared__ unsigned short sAhi[16 * KP];   // 8448 B
  __shared__ unsigned short sBhi[16 * KP];   // 8448 B
  __shared__ float sBL[SPB * 64];            // 4096 B

  const int t    = threadIdx.x;
  const int lane = t & 63;
  const int wv   = t >> 6;                   // 0..15
  const int ln15 = lane & 15;
  const int quad = lane >> 4;
  const int bbase = blockIdx.x * SPB;
  const int b = bbase + wv;                  // this wave's sample

  //===== Register perm codes (both used by Phase A and Phase B) =====
  const unsigned code0 = permCode(lane);
  const unsigned code1 = permCode(lane + 64);  // used only when lane < 56

  //===== Hoist: both Gumbel perturbations + alpha softmax stats =====
  float gb, ga, la, ea, Za;
  {
    float ub_ = ub[(size_t)b * 64 + lane];
    float ua_ = ua[(size_t)b * 64 + lane];
    gb = -logf(-logf(fmaxf(ub_, 1e-10f)));   // precise: selection path
    ga = -logf(-logf(fmaxf(ua_, 1e-10f)));   // precise: selection path
    la = alog[lane];
    ea = __expf(la);
    Za = dppRedSum(ea);
  }

  //===== Phase A: alpha top-5 + PL, fused with Phase H =====
  float lpA;
  {
    int jr[5];
    lpA = selectPL5(la, ea, Za, ga, out + (size_t)b * 128, lane, code0, code1, jr);

    //===== Phase H: h[s][0..127] = silu(b1 + sum 5 W1 rows) -> sAhi =====
    int jcol = lane * 2;            // cols jcol, jcol+1
    float2 a = *(const float2*)(b1 + jcol);
#pragma unroll
    for (int r = 0; r < 5; ++r) {
      float2 w = *(const float2*)(W1 + (size_t)jr[r] * 128 + jcol);
      a.x += w.x; a.y += w.y;
    }
    unsigned h0 = bround(siluf(a.x));
    unsigned h1 = bround(siluf(a.y));
    *(unsigned*)&sAhi[wv * KP + jcol] = h0 | (h1 << 16);
  }

  //----- GEMM1 prefetch: ksteps 0,1 issued before the barrier -----
  s16x8 p1h[3], p1l[3];
  if (wv < 4) {
    const unsigned short* tb = wt + OFF_W2 + (size_t)(wv * 4) * 1024;
    p1h[0] = ((const s16x8*)tb)[lane];
    p1l[0] = ((const s16x8*)(tb + 512))[lane];
    p1h[1] = ((const s16x8*)(tb + 1024))[lane];
    p1l[1] = ((const s16x8*)(tb + 1536))[lane];
  }
  __syncthreads();                           // barrier 1: sAhi(h) ready

  //===== GEMM1: ctx(16x64) = h @ W2 + b2  (K=128, waves 0-3, pipelined) =====
  if (wv < 4) {
    f32x4 acc = {0.f, 0.f, 0.f, 0.f};
#pragma unroll
    for (int ks = 0; ks < 4; ++ks) {
      int ko = ks * 32 + quad * 8;
      s16x8 ah = *(const s16x8*)&sAhi[ln15 * KP + ko];
      if (ks + 2 < 4) {
        const unsigned short* tn = wt + OFF_W2 + (size_t)(wv * 4 + ks + 2) * 1024;
        p1h[(ks + 2) % 3] = ((const s16x8*)tn)[lane];
        p1l[(ks + 2) % 3] = ((const s16x8*)(tn + 512))[lane];
      }
      acc = MFMA16(ah, p1h[ks % 3], acc, 0, 0, 0);
      acc = MFMA16(ah, p1l[ks % 3], acc, 0, 0, 0);
    }
    int col = wv * 16 + ln15;
    float bias = b2[col];
#pragma unroll
    for (int r = 0; r < 4; ++r)
      sBhi[(quad * 4 + r) * KP + col] = bround(acc[r] + bias);
  }

  //----- GEMM2 prefetch: both ksteps issued before the barrier -----
  s16x8 p2h[2], p2l[2];
  {
    const unsigned short* tb = wt + OFF_V1 + (size_t)(wv * 2) * 1024;
    p2h[0] = ((const s16x8*)tb)[lane];
    p2l[0] = ((const s16x8*)(tb + 512))[lane];
    p2h[1] = ((const s16x8*)(tb + 1024))[lane];
    p2l[1] = ((const s16x8*)(tb + 1536))[lane];
  }
  __syncthreads();                           // barrier 2: sBhi(ctx) ready

  //===== GEMM2: z1(16x256) = silu(ctx @ V1[64:,:] + c1)  (K=64, 1 tile/wave) =====
  {
    f32x4 acc = {0.f, 0.f, 0.f, 0.f};
#pragma unroll
    for (int ks = 0; ks < 2; ++ks) {
      int ko = ks * 32 + quad * 8;
      s16x8 ah = *(const s16x8*)&sBhi[ln15 * KP + ko];
      acc = MFMA16(ah, p2h[ks], acc, 0, 0, 0);
      acc = MFMA16(ah, p2l[ks], acc, 0, 0, 0);
    }
    int col = wv * 16 + ln15;
    float bias = c1[col];
#pragma unroll
    for (int r = 0; r < 4; ++r)
      sAhi[(quad * 4 + r) * KP + col] = bround(siluf(acc[r] + bias));
  }

  //----- GEMM3 prefetch: ksteps 0,1 issued before the barrier -----
  s16x8 p3h[3], p3l[3];
  {
    const unsigned short* tb = wt + OFF_V2 + (size_t)(wv * 8) * 1024;
    p3h[0] = ((const s16x8*)tb)[lane];
    p3l[0] = ((const s16x8*)(tb + 512))[lane];
    p3h[1] = ((const s16x8*)(tb + 1024))[lane];
    p3l[1] = ((const s16x8*)(tb + 1536))[lane];
  }
  __syncthreads();                           // barrier 3: sAhi(z1) ready

  //===== GEMM3: z2(16x256) = silu(z1 @ V2 + c2)  (K=256, pipelined) =====
  {
    f32x4 acc = {0.f, 0.f, 0.f, 0.f};
#pragma unroll
    for (int ks = 0; ks < 8; ++ks) {
      int ko = ks * 32 + quad * 8;
      s16x8 ah = *(const s16x8*)&sAhi[ln15 * KP + ko];
      if (ks + 2 < 8) {
        const unsigned short* tn = wt + OFF_V2 + (size_t)(wv * 8 + ks + 2) * 1024;
        p3h[(ks + 2) % 3] = ((const s16x8*)tn)[lane];
        p3l[(ks + 2) % 3] = ((const s16x8*)(tn + 512))[lane];
      }
      acc = MFMA16(ah, p3h[ks % 3], acc, 0, 0, 0);
      acc = MFMA16(ah, p3l[ks % 3], acc, 0, 0, 0);
    }
    int col = wv * 16 + ln15;
    float bias = c2[col];
#pragma unroll
    for (int r = 0; r < 4; ++r)
      sBhi[(quad * 4 + r) * KP + col] = bround(siluf(acc[r] + bias));
  }

  //----- GEMM4 prefetch: ksteps 0,1 issued before the barrier -----
  s16x8 p4h[3], p4l[3];
  if (wv < 4) {
    const unsigned short* tb = wt + OFF_V3 + (size_t)(wv * 8) * 1024;
    p4h[0] = ((const s16x8*)tb)[lane];
    p4l[0] = ((const s16x8*)(tb + 512))[lane];
    p4h[1] = ((const s16x8*)(tb + 1024))[lane];
    p4l[1] = ((const s16x8*)(tb + 1536))[lane];
  }
  __syncthreads();                           // barrier 4: sBhi(z2) ready

  //===== GEMM4: beta_logits(16x64) = z2 @ V3 + c3  (K=256, waves 0-3) =====
  if (wv < 4) {
    f32x4 acc = {0.f, 0.f, 0.f, 0.f};
#pragma unroll
    for (int ks = 0; ks < 8; ++ks) {
      int ko = ks * 32 + quad * 8;
      s16x8 ah = *(const s16x8*)&sBhi[ln15 * KP + ko];
      if (ks + 2 < 8) {
        const unsigned short* tn = wt + OFF_V3 + (size_t)(wv * 8 + ks + 2) * 1024;
        p4h[(ks + 2) % 3] = ((const s16x8*)tn)[lane];
        p4l[(ks + 2) % 3] = ((const s16x8*)(tn + 512))[lane];
      }
      acc = MFMA16(ah, p4h[ks % 3], acc, 0, 0, 0);
      acc = MFMA16(ah, p4l[ks % 3], acc, 0, 0, 0);
    }
    int col = wv * 16 + ln15;
    float bias = c3[col];
#pragma unroll
    for (int r = 0; r < 4; ++r)
      sBL[(quad * 4 + r) * 64 + col] = acc[r] + bias;
  }
  __syncthreads();                           // barrier 5: sBL ready

  //===== Phase B: beta top-5 + PL (1 sample per wave, hoisted Gumbel) =====
  {
    float blv = sBL[wv * 64 + lane];
    float eb = __expf(blv);
    float Zb = dppRedSum(eb);
    float lp = selectPL5(blv, eb, Zb, gb, out + (size_t)b * 128 + 64, lane,
                         code0, code1, nullptr);
    if (lane == 0)
      out[(size_t)8192 * 128 + b] = lpA + lp;
  }
}

//====== Old-style helpers kept for the fallback kernel only ======
__device__ __forceinline__ float permSum(const float se0, const float se1,
                                         const float se2, const float se3,
                                         const float se4, float Z, int lane) {
  float psum = 0.0f;
#pragma unroll
  for (int pp = 0; pp < 2; ++pp) {
    int p = lane + pp * 64;
    if (p < 120) {
      int rem = p;
      unsigned avail = 0x43210u;
      float c = 0.0f;
      float prod = Z;
#pragma unroll
      for (int j = 0; j < 4; ++j) {
        const int fct = (j == 0) ? 24 : (j == 1) ? 6 : (j == 2) ? 2 : 1;
        int q = rem / fct; rem -= q * fct;
        int sh = q * 4;
        int dg = (avail >> sh) & 0xF;
        avail = (avail & ((1u << sh) - 1u)) | ((avail >> (sh + 4)) << sh);
        float ev = (dg == 0) ? se0 : (dg == 1) ? se1 : (dg == 2) ? se2
                 : (dg == 3) ? se3 : se4;
        c += ev;
        prod *= (Z - c);
      }
      psum += __builtin_amdgcn_rcpf(prod);
    }
  }
  return psum;
}

__device__ __forceinline__ float selectAndPL(float lv, float ev, float Z,
                                             float g,
                                             float* __restrict__ gout,
                                             int lane,
                                             float* __restrict__ sValsRow,
                                             float* __restrict__ sSelERow,
                                             int* __restrict__ selIdxRow) {
  float v = lv + g;
  sValsRow[lane] = v;
  int rank = 0;
#pragma unroll
  for (int j = 0; j < 16; ++j) {
    float4 w = *(const float4*)&sValsRow[j * 4];
    int base = j * 4;
    rank += (w.x > v || (w.x == v && base + 0 < lane)) ? 1 : 0;
    rank += (w.y > v || (w.y == v && base + 1 < lane)) ? 1 : 0;
    rank += (w.z > v || (w.z == v && base + 2 < lane)) ? 1 : 0;
    rank += (w.w > v || (w.w == v && base + 3 < lane)) ? 1 : 0;
  }
  bool sel = rank < 5;
  gout[lane] = sel ? 1.0f : 0.0f;
  if (sel) {
    sSelERow[rank] = ev;
    sSelERow[8 + rank] = lv;
    if (selIdxRow) selIdxRow[rank] = lane;
  }
  float se0 = sSelERow[0], se1 = sSelERow[1], se2 = sSelERow[2],
        se3 = sSelERow[3], se4 = sSelERow[4];
  float sl = sSelERow[8] + sSelERow[9] + sSelERow[10] + sSelERow[11]
           + sSelERow[12];
  float S = waveSum(permSum(se0, se1, se2, se3, se4, Z, lane));
  return sl + __logf(S);
}

//================= Fallback (R4-style kernel, no ws needed) =================
#define SPB4 4
__global__ __launch_bounds__(256, 8)
void pcf_small(const float* __restrict__ ua, const float* __restrict__ ub,
               const float* __restrict__ alog, const float* __restrict__ W1,
               const float* __restrict__ b1, const float* __restrict__ W2,
               const float* __restrict__ b2, const float* __restrict__ V1,
               const float* __restrict__ c1, const float* __restrict__ V2,
               const float* __restrict__ c2, const float* __restrict__ V3,
               const float* __restrict__ c3, float* __restrict__ out)
{
  __shared__ float sA[SPB4 * 256];
  __shared__ float sB[SPB4 * 256];
  __shared__ float sP[4 * 256];
  __shared__ float sVals[4 * 64];
  __shared__ float sSelE[4 * 16];
  __shared__ int   sSelA[SPB4 * 5];
  __shared__ float sLpA[SPB4];

  const int t    = threadIdx.x;
  const int lane = t & 63;
  const int wv   = t >> 6;
  const int bbase = blockIdx.x * SPB4;

  float* sValsRow = &sVals[wv * 64];
  float* sSelERow = &sSelE[wv * 16];

  {
    float la = alog[lane];
    float ea = __expf(la);
    float Za = waveSum(ea);
    int b = bbase + wv;
    float u = ua[(size_t)b * 64 + lane];
    float g = -logf(-logf(fmaxf(u, 1e-10f)));
    float lp = selectAndPL(la, ea, Za, g, out + (size_t)b * 128, lane,
                           sValsRow, sSelERow, &sSelA[wv * 5]);
    if (lane == 0) sLpA[wv] = lp;
  }
  __syncthreads();
  {
    int s = wv;
    int i0 = sSelA[s * 5 + 0], i1 = sSelA[s * 5 + 1], i2 = sSelA[s * 5 + 2];
    int i3 = sSelA[s * 5 + 3], i4 = sSelA[s * 5 + 4];
#pragma unroll
    for (int jh = 0; jh < 2; ++jh) {
      int j = lane + jh * 64;
      float acc = b1[j] + W1[i0 * 128 + j] + W1[i1 * 128 + j]
                + W1[i2 * 128 + j] + W1[i3 * 128 + j] + W1[i4 * 128 + j];
      sA[s * 128 + j] = siluf(acc);
    }
  }
  __syncthreads();
  {
    float acc[SPB4] = {};
    const int kb = 32 * wv;
#pragma unroll 2
    for (int m = 0; m < 8; ++m) {
      int k0 = kb + 4 * m;
      float w0 = W2[(k0 + 0) * 64 + lane];
      float w1 = W2[(k0 + 1) * 64 + lane];
      float w2 = W2[(k0 + 2) * 64 + lane];
      float w3 = W2[(k0 + 3) * 64 + lane];
#pragma unroll
      for (int s = 0; s < SPB4; ++s) {
        float4 x = *(float4*)&sA[s * 128 + k0];
        acc[s] += x.x * w0 + x.y * w1 + x.z * w2 + x.w * w3;
      }
    }
#pragma unroll
    for (int s = 0; s < SPB4; ++s) sP[wv * 256 + s * 64 + lane] = acc[s];
  }
  __syncthreads();
  {
    int o = t;
    float v = b2[o & 63] + sP[o] + sP[256 + o] + sP[512 + o] + sP[768 + o];
    sB[o] = v;
  }
  __syncthreads();
  {
    const int c = 64 * wv + lane;
    float acc[SPB4];
    float cb = c1[c];
#pragma unroll
    for (int s = 0; s < SPB4; ++s) acc[s] = cb;
    const float* wp = V1 + (size_t)64 * 256 + c;
#pragma unroll 4
    for (int m = 0; m < 16; ++m) {
      int k0 = 4 * m;
      float w0 = wp[(k0 + 0) * 256];
      float w1 = wp[(k0 + 1) * 256];
      float w2 = wp[(k0 + 2) * 256];
      float w3 = wp[(k0 + 3) * 256];
#pragma unroll
      for (int s = 0; s < SPB4; ++s) {
        float4 x = *(float4*)&sB[s * 64 + k0];
        acc[s] += x.x * w0 + x.y * w1 + x.z * w2 + x.w * w3;
      }
    }
#pragma unroll
    for (int s = 0; s < SPB4; ++s) sA[s * 256 + c] = siluf(acc[s]);
  }
  __syncthreads();
  {
    const int c = 64 * wv + lane;
    float acc[SPB4];
    float cb = c2[c];
#pragma unroll
    for (int s = 0; s < SPB4; ++s) acc[s] = cb;
    const float* wp = V2 + c;
#pragma unroll 4
    for (int m = 0; m < 64; ++m) {
      int k0 = 4 * m;
      float w0 = wp[(size_t)(k0 + 0) * 256];
      float w1 = wp[(size_t)(k0 + 1) * 256];
      float w2 = wp[(size_t)(k0 + 2) * 256];
      float w3 = wp[(size_t)(k0 + 3) * 256];
#pragma unroll
      for (int s = 0; s < SPB4; ++s) {
        float4 x = *(float4*)&sA[s * 256 + k0];
        acc[s] += x.x * w0 + x.y * w1 + x.z * w2 + x.w * w3;
      }
    }
#pragma unroll
    for (int s = 0; s < SPB4; ++s) sB[s * 256 + c] = siluf(acc[s]);
  }
  __syncthreads();
  {
    float acc[SPB4] = {};
    const int kb = 64 * wv;
#pragma unroll 4
    for (int m = 0; m < 16; ++m) {
      int k0 = kb + 4 * m;
      float w0 = V3[(k0 + 0) * 64 + lane];
      float w1 = V3[(k0 + 1) * 64 + lane];
      float w2 = V3[(k0 + 2) * 64 + lane];
      float w3 = V3[(k0 + 3) * 64 + lane];
#pragma unroll
      for (int s = 0; s < SPB4; ++s) {
        float4 x = *(float4*)&sB[s * 256 + k0];
        acc[s] += x.x * w0 + x.y * w1 + x.z * w2 + x.w * w3;
      }
    }
#pragma unroll
    for (int s = 0; s < SPB4; ++s) sP[wv * 256 + s * 64 + lane] = acc[s];
  }
  __syncthreads();
  {
    int b = bbase + wv;
    float blv = c3[lane] + sP[wv * 64 + lane] + sP[256 + wv * 64 + lane]
              + sP[512 + wv * 64 + lane] + sP[768 + wv * 64 + lane];
    float eb = __expf(blv);
    float Zb = waveSum(eb);
    float u = ub[(size_t)b * 64 + lane];
    float g = -logf(-logf(fmaxf(u, 1e-10f)));
    float lp = selectAndPL(blv, eb, Zb, g, out + (size_t)b * 128 + 64, lane,
                           sValsRow, sSelERow, nullptr);
    if (lane == 0)
      out[(size_t)8192 * 128 + b] = sLpA[wv] + lp;
  }
}

extern "C" void kernel_launch(void* const* d_in, const int* in_sizes, int n_in,
                              void* d_out, int out_size, void* d_ws, size_t ws_size,
                              hipStream_t stream) {
  const float* ua   = (const float*)d_in[0];
  const float* ub   = (const float*)d_in[1];
  const float* alog = (const float*)d_in[2];
  const float* W1   = (const float*)d_in[3];
  const float* b1   = (const float*)d_in[4];
  const float* W2   = (const float*)d_in[5];
  const float* b2   = (const float*)d_in[6];
  const float* V1   = (const float*)d_in[7];
  const float* c1   = (const float*)d_in[8];
  const float* V2   = (const float*)d_in[9];
  const float* c2   = (const float*)d_in[10];
  const float* V3   = (const float*)d_in[11];
  const float* c3   = (const float*)d_in[12];
  float* out = (float*)d_out;

  if (ws_size >= (size_t)WS_USHORTS * 2) {
    unsigned short* wt = (unsigned short*)d_ws;
    pcf_prep<<<dim3(52), dim3(256), 0, stream>>>(W2, V1, V2, V3, wt);
    pcf_mfma<<<dim3(8192 / SPB), dim3(NTH), 0, stream>>>(
        ua, ub, alog, W1, b1, b2, c1, c2, c3, wt, out);
  } else {
    pcf_small<<<dim3(8192 / SPB4), dim3(256), 0, stream>>>(
        ua, ub, alog, W1, b1, W2, b2, V1, c1, V2, c2, V3, c3, out);
  }
}

// Round 6
// 99.313 us; speedup vs baseline: 1.0357x; 1.0357x over previous
//
#include <hip/hip_runtime.h>
#include <math.h>

#define NTH 1024                    // 16 waves per block
#define KP 264                      // LDS row stride (ushorts), padded
#define SPB 16                      // samples per block (fills M=16 MFMA tiles)
#define OFF_W2 0                    // 4 tiles x 4 ksteps
#define OFF_V1 16384                // 16 x 2
#define OFF_V2 49152                // 16 x 8
#define OFF_V3 180224               // 4 x 8
#define WS_USHORTS 212992
#define MFMA16 __builtin_amdgcn_mfma_f32_16x16x32_bf16

typedef __attribute__((ext_vector_type(8))) short s16x8;
typedef __attribute__((ext_vector_type(8))) unsigned short u16x8;
typedef __attribute__((ext_vector_type(4))) float f32x4;

__device__ __forceinline__ float waveSum(float v) {
#pragma unroll
  for (int off = 32; off; off >>= 1) v += __shfl_xor(v, off, 64);
  return v;
}

__device__ __forceinline__ float waveMax(float v) {
#pragma unroll
  for (int off = 32; off; off >>= 1) v = fmaxf(v, __shfl_xor(v, off, 64));
  return v;
}

// Fast silu: __expf error ~1e-7 rel; output is bf16-rounded (2^-9) anyway.
__device__ __forceinline__ float siluf(float x) { return x / (1.0f + __expf(-x)); }

// Round fp32 -> bf16 (RNE), return bits.
__device__ __forceinline__ unsigned short bround(float x) {
  unsigned u = __float_as_uint(x);
  return (unsigned short)((u + 0x7FFFu + ((u >> 16) & 1u)) >> 16);
}

// Split fp32 into bf16 hi + bf16 lo (round-to-nearest-even).
__device__ __forceinline__ void bsplit(float x, unsigned short& h, unsigned short& l) {
  unsigned u = __float_as_uint(x);
  unsigned hb = (u + 0x7FFFu + ((u >> 16) & 1u)) >> 16;
  float hf = __uint_as_float(hb << 16);
  float lf = x - hf;
  unsigned ul = __float_as_uint(lf);
  unsigned lb = (ul + 0x7FFFu + ((ul >> 16) & 1u)) >> 16;
  h = (unsigned short)hb; l = (unsigned short)lb;
}

//========= Table-driven permSum (digits precomputed in LDS, 3b each) =========
// Digit order identical to the original factorial decode -> bit-exact psum.
__device__ __forceinline__ float permSumT(const float se0, const float se1,
                                          const float se2, const float se3,
                                          const float se4, float Z, int lane,
                                          const unsigned short* __restrict__ sPerm) {
  float psum = 0.0f;
#pragma unroll
  for (int pp = 0; pp < 2; ++pp) {
    int p = lane + pp * 64;
    if (p < 120) {
      unsigned code = sPerm[p];
      float c = 0.0f;
      float prod = Z;
#pragma unroll
      for (int j = 0; j < 4; ++j) {
        int dg = (code >> (3 * j)) & 7;
        float ev = (dg == 0) ? se0 : (dg == 1) ? se1 : (dg == 2) ? se2
                 : (dg == 3) ? se3 : se4;
        c += ev;
        prod *= (Z - c);
      }
      psum += __builtin_amdgcn_rcpf(prod);
    }
  }
  return psum;
}

// One ballot-argmax extraction: returns lane index of max(vv) (ties -> lowest
// lane, matching jax.lax.top_k), broadcasts that lane's (ev, lv) via readlane,
// and masks the winner out of vv.
__device__ __forceinline__ int extractMax(float& vv, float ev, float lv,
                                          int lane, float& seo, float& lvo) {
  float m = waveMax(vv);
  unsigned long long b = __ballot(vv == m);
  int j = __ffsll(b) - 1;
  seo = __uint_as_float(__builtin_amdgcn_readlane(__float_as_uint(ev), j));
  lvo = __uint_as_float(__builtin_amdgcn_readlane(__float_as_uint(lv), j));
  vv = (lane == j) ? -INFINITY : vv;
  return j;
}

// Register-based Gumbel top-5 + exact PL log-prob (no LDS scratch, no
// divergent writes). Extraction order == rank order, so sl / se ordering and
// all reduction orders are bit-identical to the previous rank-based path.
__device__ __forceinline__ float selectPL5(float lv, float ev, float Z, float g,
                                           float* __restrict__ gout, int lane,
                                           const unsigned short* __restrict__ sPerm,
                                           int* __restrict__ jr /*int[5] or null*/) {
  float vv = lv + g;
  unsigned long long sb = 0;
  float se0, se1, se2, se3, se4, l0, l1, l2, l3, l4;
  int j;
  j = extractMax(vv, ev, lv, lane, se0, l0); sb |= 1ull << j; if (jr) jr[0] = j;
  j = extractMax(vv, ev, lv, lane, se1, l1); sb |= 1ull << j; if (jr) jr[1] = j;
  j = extractMax(vv, ev, lv, lane, se2, l2); sb |= 1ull << j; if (jr) jr[2] = j;
  j = extractMax(vv, ev, lv, lane, se3, l3); sb |= 1ull << j; if (jr) jr[3] = j;
  j = extractMax(vv, ev, lv, lane, se4, l4); sb |= 1ull << j; if (jr) jr[4] = j;
  gout[lane] = (float)((sb >> lane) & 1ull);
  float sl = (((l0 + l1) + l2) + l3) + l4;   // left-assoc, rank order (as before)
  float S = waveSum(permSumT(se0, se1, se2, se3, se4, Z, lane, sPerm));
  return sl + __logf(S);
}

//============ Prep: tile + split weights into fragment order ============
__global__ __launch_bounds__(256)
void pcf_prep(const float* __restrict__ W2, const float* __restrict__ V1,
              const float* __restrict__ V2, const float* __restrict__ V3,
              unsigned short* __restrict__ ws)
{
  int tid = blockIdx.x * 256 + threadIdx.x;
  const float* src; int N, Ks, dstoff, r;
  if (tid < 1024)       { src = W2;            N = 64;  Ks = 4; dstoff = OFF_W2; r = tid; }
  else if (tid < 3072)  { src = V1 + 64 * 256; N = 256; Ks = 2; dstoff = OFF_V1; r = tid - 1024; }
  else if (tid < 11264) { src = V2;            N = 256; Ks = 8; dstoff = OFF_V2; r = tid - 3072; }
  else                  { src = V3;            N = 64;  Ks = 8; dstoff = OFF_V3; r = tid - 11264; }
  int lane = r & 63, ts = r >> 6;
  int ks = ts % Ks, ct = ts / Ks;
  int n = ct * 16 + (lane & 15);
  int k0 = ks * 32 + (lane >> 4) * 8;
  u16x8 hv, lv;
#pragma unroll
  for (int j = 0; j < 8; ++j) {
    float x = src[(size_t)(k0 + j) * N + n];
    unsigned short h, l;
    bsplit(x, h, l);
    hv[j] = h; lv[j] = l;
  }
  unsigned short* dst = ws + dstoff + (size_t)ts * 1024 + lane * 8;
  *(u16x8*)dst = hv;
  *(u16x8*)(dst + 512) = lv;
}

//============ Main: 16 samples/block, 16 waves, MFMA (act hi, wt hi+lo) =====
__global__ __launch_bounds__(NTH, 8)
void pcf_mfma(const float* __restrict__ ua, const float* __restrict__ ub,
              const float* __restrict__ alog, const float* __restrict__ W1,
              const float* __restrict__ b1, const float* __restrict__ b2,
              const float* __restrict__ c1, const float* __restrict__ c2,
              const float* __restrict__ c3,
              const unsigned short* __restrict__ wt, float* __restrict__ out)
{
  __shared__ unsigned short sAhi[16 * KP];   // 8448 B
  __shared__ unsigned short sBhi[16 * KP];   // 8448 B
  __shared__ float sBL[SPB * 64];            // 4096 B
  __shared__ unsigned short sPerm[128];      // 256 B  perm digit codes

  const int t    = threadIdx.x;
  const int lane = t & 63;
  const int wv   = t >> 6;                   // 0..15
  const int ln15 = lane & 15;
  const int quad = lane >> 4;
  const int bbase = blockIdx.x * SPB;

  //===== Init: perm-digit table (bit-exact match of factorial decode) =====
  if (t < 120) {
    int rem = t;
    unsigned avail = 0x43210u, code = 0;
#pragma unroll
    for (int j = 0; j < 4; ++j) {
      const int fct = (j == 0) ? 24 : (j == 1) ? 6 : (j == 2) ? 2 : 1;
      int q = rem / fct; rem -= q * fct;
      int sh = q * 4;
      unsigned dg = (avail >> sh) & 0xF;
      avail = (avail & ((1u << sh) - 1u)) | ((avail >> (sh + 4)) << sh);
      code |= dg << (3 * j);
    }
    sPerm[t] = (unsigned short)code;
  }

  //===== Hoist: beta Gumbel perturbation + alpha uniform load =====
  float gb, uA;
  {
    int b = bbase + wv;
    float u = ub[(size_t)b * 64 + lane];
    gb = -logf(-logf(fmaxf(u, 1e-10f)));     // precise: selection path
    uA = ua[(size_t)b * 64 + lane];
  }
  __syncthreads();

  //===== Phase A: alpha top-5 + PL, fused with Phase H (same wave owns
  //===== sample s == wv; no cross-wave deps until GEMM1) =====
  float lpA;
  {
    float la = alog[lane];
    float ea = __expf(la);
    float Za = waveSum(ea);
    int b = bbase + wv;
    float ga = -logf(-logf(fmaxf(uA, 1e-10f)));  // precise: selection path
    int jr[5];
    lpA = selectPL5(la, ea, Za, ga, out + (size_t)b * 128, lane, sPerm, jr);

    //===== Phase H: h[s][0..127] = silu(b1 + sum 5 W1 rows) -> sAhi =====
    int jcol = lane * 2;            // cols jcol, jcol+1
    float2 a = *(const float2*)(b1 + jcol);
#pragma unroll
    for (int r = 0; r < 5; ++r) {
      float2 w = *(const float2*)(W1 + (size_t)jr[r] * 128 + jcol);
      a.x += w.x; a.y += w.y;
    }
    unsigned h0 = bround(siluf(a.x));
    unsigned h1 = bround(siluf(a.y));
    *(unsigned*)&sAhi[wv * KP + jcol] = h0 | (h1 << 16);
  }
  __syncthreads();

  //===== GEMM1: ctx(16x64) = h @ W2 + b2  (K=128, waves 0-3) =====
  if (wv < 4) {
    f32x4 acc = {0.f, 0.f, 0.f, 0.f};
#pragma unroll
    for (int ks = 0; ks < 4; ++ks) {
      int ko = ks * 32 + quad * 8;
      s16x8 ah = *(const s16x8*)&sAhi[ln15 * KP + ko];
      const unsigned short* tsb = wt + OFF_W2 + (size_t)(wv * 4 + ks) * 1024;
      s16x8 bh = ((const s16x8*)tsb)[lane];
      s16x8 bl = ((const s16x8*)(tsb + 512))[lane];
      acc = MFMA16(ah, bh, acc, 0, 0, 0);
      acc = MFMA16(ah, bl, acc, 0, 0, 0);
    }
    int col = wv * 16 + ln15;
    float bias = b2[col];
#pragma unroll
    for (int r = 0; r < 4; ++r)
      sBhi[(quad * 4 + r) * KP + col] = bround(acc[r] + bias);
  }
  __syncthreads();

  //===== GEMM2: z1(16x256) = silu(ctx @ V1[64:,:] + c1)  (K=64, 1 tile/wave) =====
  {
    f32x4 acc = {0.f, 0.f, 0.f, 0.f};
#pragma unroll
    for (int ks = 0; ks < 2; ++ks) {
      int ko = ks * 32 + quad * 8;
      s16x8 ah = *(const s16x8*)&sBhi[ln15 * KP + ko];
      const unsigned short* tsb = wt + OFF_V1 + (size_t)(wv * 2 + ks) * 1024;
      s16x8 bh = ((const s16x8*)tsb)[lane];
      s16x8 bl = ((const s16x8*)(tsb + 512))[lane];
      acc = MFMA16(ah, bh, acc, 0, 0, 0);
      acc = MFMA16(ah, bl, acc, 0, 0, 0);
    }
    int col = wv * 16 + ln15;
    float bias = c1[col];
#pragma unroll
    for (int r = 0; r < 4; ++r)
      sAhi[(quad * 4 + r) * KP + col] = bround(siluf(acc[r] + bias));
  }
  __syncthreads();

  //===== GEMM3: z2(16x256) = silu(z1 @ V2 + c2)  (K=256, 1 tile/wave) =====
  {
    f32x4 acc = {0.f, 0.f, 0.f, 0.f};
#pragma unroll 4
    for (int ks = 0; ks < 8; ++ks) {
      int ko = ks * 32 + quad * 8;
      s16x8 ah = *(const s16x8*)&sAhi[ln15 * KP + ko];
      const unsigned short* tsb = wt + OFF_V2 + (size_t)(wv * 8 + ks) * 1024;
      s16x8 bh = ((const s16x8*)tsb)[lane];
      s16x8 bl = ((const s16x8*)(tsb + 512))[lane];
      acc = MFMA16(ah, bh, acc, 0, 0, 0);
      acc = MFMA16(ah, bl, acc, 0, 0, 0);
    }
    int col = wv * 16 + ln15;
    float bias = c2[col];
#pragma unroll
    for (int r = 0; r < 4; ++r)
      sBhi[(quad * 4 + r) * KP + col] = bround(siluf(acc[r] + bias));
  }
  __syncthreads();

  //===== GEMM4: beta_logits(16x64) = z2 @ V3 + c3  (K=256, waves 0-3) =====
  if (wv < 4) {
    f32x4 acc = {0.f, 0.f, 0.f, 0.f};
#pragma unroll
    for (int ks = 0; ks < 8; ++ks) {
      int ko = ks * 32 + quad * 8;
      s16x8 ah = *(const s16x8*)&sBhi[ln15 * KP + ko];
      const unsigned short* tsb = wt + OFF_V3 + (size_t)(wv * 8 + ks) * 1024;
      s16x8 bh = ((const s16x8*)tsb)[lane];
      s16x8 bl = ((const s16x8*)(tsb + 512))[lane];
      acc = MFMA16(ah, bh, acc, 0, 0, 0);
      acc = MFMA16(ah, bl, acc, 0, 0, 0);
    }
    int col = wv * 16 + ln15;
    float bias = c3[col];
#pragma unroll
    for (int r = 0; r < 4; ++r)
      sBL[(quad * 4 + r) * 64 + col] = acc[r] + bias;
  }
  __syncthreads();

  //===== Phase B: beta top-5 + PL (1 sample per wave, hoisted Gumbel) =====
  {
    int b = bbase + wv;
    float blv = sBL[wv * 64 + lane];
    float eb = __expf(blv);
    float Zb = waveSum(eb);
    float lp = selectPL5(blv, eb, Zb, gb, out + (size_t)b * 128 + 64, lane,
                         sPerm, nullptr);
    if (lane == 0)
      out[(size_t)8192 * 128 + b] = lpA + lp;
  }
}

//====== Old-style helpers kept for the fallback kernel only ======
__device__ __forceinline__ float permSum(const float se0, const float se1,
                                         const float se2, const float se3,
                                         const float se4, float Z, int lane) {
  float psum = 0.0f;
#pragma unroll
  for (int pp = 0; pp < 2; ++pp) {
    int p = lane + pp * 64;
    if (p < 120) {
      int rem = p;
      unsigned avail = 0x43210u;
      float c = 0.0f;
      float prod = Z;
#pragma unroll
      for (int j = 0; j < 4; ++j) {
        const int fct = (j == 0) ? 24 : (j == 1) ? 6 : (j == 2) ? 2 : 1;
        int q = rem / fct; rem -= q * fct;
        int sh = q * 4;
        int dg = (avail >> sh) & 0xF;
        avail = (avail & ((1u << sh) - 1u)) | ((avail >> (sh + 4)) << sh);
        float ev = (dg == 0) ? se0 : (dg == 1) ? se1 : (dg == 2) ? se2
                 : (dg == 3) ? se3 : se4;
        c += ev;
        prod *= (Z - c);
      }
      psum += __builtin_amdgcn_rcpf(prod);
    }
  }
  return psum;
}

__device__ __forceinline__ float selectAndPL(float lv, float ev, float Z,
                                             float g,
                                             float* __restrict__ gout,
                                             int lane,
                                             float* __restrict__ sValsRow,
                                             float* __restrict__ sSelERow,
                                             int* __restrict__ selIdxRow) {
  float v = lv + g;
  sValsRow[lane] = v;
  int rank = 0;
#pragma unroll
  for (int j = 0; j < 16; ++j) {
    float4 w = *(const float4*)&sValsRow[j * 4];
    int base = j * 4;
    rank += (w.x > v || (w.x == v && base + 0 < lane)) ? 1 : 0;
    rank += (w.y > v || (w.y == v && base + 1 < lane)) ? 1 : 0;
    rank += (w.z > v || (w.z == v && base + 2 < lane)) ? 1 : 0;
    rank += (w.w > v || (w.w == v && base + 3 < lane)) ? 1 : 0;
  }
  bool sel = rank < 5;
  gout[lane] = sel ? 1.0f : 0.0f;
  if (sel) {
    sSelERow[rank] = ev;
    sSelERow[8 + rank] = lv;
    if (selIdxRow) selIdxRow[rank] = lane;
  }
  float se0 = sSelERow[0], se1 = sSelERow[1], se2 = sSelERow[2],
        se3 = sSelERow[3], se4 = sSelERow[4];
  float sl = sSelERow[8] + sSelERow[9] + sSelERow[10] + sSelERow[11]
           + sSelERow[12];
  float S = waveSum(permSum(se0, se1, se2, se3, se4, Z, lane));
  return sl + __logf(S);
}

//================= Fallback (R4-style kernel, no ws needed) =================
#define SPB4 4
__global__ __launch_bounds__(256, 8)
void pcf_small(const float* __restrict__ ua, const float* __restrict__ ub,
               const float* __restrict__ alog, const float* __restrict__ W1,
               const float* __restrict__ b1, const float* __restrict__ W2,
               const float* __restrict__ b2, const float* __restrict__ V1,
               const float* __restrict__ c1, const float* __restrict__ V2,
               const float* __restrict__ c2, const float* __restrict__ V3,
               const float* __restrict__ c3, float* __restrict__ out)
{
  __shared__ float sA[SPB4 * 256];
  __shared__ float sB[SPB4 * 256];
  __shared__ float sP[4 * 256];
  __shared__ float sVals[4 * 64];
  __shared__ float sSelE[4 * 16];
  __shared__ int   sSelA[SPB4 * 5];
  __shared__ float sLpA[SPB4];

  const int t    = threadIdx.x;
  const int lane = t & 63;
  const int wv   = t >> 6;
  const int bbase = blockIdx.x * SPB4;

  float* sValsRow = &sVals[wv * 64];
  float* sSelERow = &sSelE[wv * 16];

  {
    float la = alog[lane];
    float ea = __expf(la);
    float Za = waveSum(ea);
    int b = bbase + wv;
    float u = ua[(size_t)b * 64 + lane];
    float g = -logf(-logf(fmaxf(u, 1e-10f)));
    float lp = selectAndPL(la, ea, Za, g, out + (size_t)b * 128, lane,
                           sValsRow, sSelERow, &sSelA[wv * 5]);
    if (lane == 0) sLpA[wv] = lp;
  }
  __syncthreads();
  {
    int s = wv;
    int i0 = sSelA[s * 5 + 0], i1 = sSelA[s * 5 + 1], i2 = sSelA[s * 5 + 2];
    int i3 = sSelA[s * 5 + 3], i4 = sSelA[s * 5 + 4];
#pragma unroll
    for (int jh = 0; jh < 2; ++jh) {
      int j = lane + jh * 64;
      float acc = b1[j] + W1[i0 * 128 + j] + W1[i1 * 128 + j]
                + W1[i2 * 128 + j] + W1[i3 * 128 + j] + W1[i4 * 128 + j];
      sA[s * 128 + j] = siluf(acc);
    }
  }
  __syncthreads();
  {
    float acc[SPB4] = {};
    const int kb = 32 * wv;
#pragma unroll 2
    for (int m = 0; m < 8; ++m) {
      int k0 = kb + 4 * m;
      float w0 = W2[(k0 + 0) * 64 + lane];
      float w1 = W2[(k0 + 1) * 64 + lane];
      float w2 = W2[(k0 + 2) * 64 + lane];
      float w3 = W2[(k0 + 3) * 64 + lane];
#pragma unroll
      for (int s = 0; s < SPB4; ++s) {
        float4 x = *(float4*)&sA[s * 128 + k0];
        acc[s] += x.x * w0 + x.y * w1 + x.z * w2 + x.w * w3;
      }
    }
#pragma unroll
    for (int s = 0; s < SPB4; ++s) sP[wv * 256 + s * 64 + lane] = acc[s];
  }
  __syncthreads();
  {
    int o = t;
    float v = b2[o & 63] + sP[o] + sP[256 + o] + sP[512 + o] + sP[768 + o];
    sB[o] = v;
  }
  __syncthreads();
  {
    const int c = 64 * wv + lane;
    float acc[SPB4];
    float cb = c1[c];
#pragma unroll
    for (int s = 0; s < SPB4; ++s) acc[s] = cb;
    const float* wp = V1 + (size_t)64 * 256 + c;
#pragma unroll 4
    for (int m = 0; m < 16; ++m) {
      int k0 = 4 * m;
      float w0 = wp[(k0 + 0) * 256];
      float w1 = wp[(k0 + 1) * 256];
      float w2 = wp[(k0 + 2) * 256];
      float w3 = wp[(k0 + 3) * 256];
#pragma unroll
      for (int s = 0; s < SPB4; ++s) {
        float4 x = *(float4*)&sB[s * 64 + k0];
        acc[s] += x.x * w0 + x.y * w1 + x.z * w2 + x.w * w3;
      }
    }
#pragma unroll
    for (int s = 0; s < SPB4; ++s) sA[s * 256 + c] = siluf(acc[s]);
  }
  __syncthreads();
  {
    const int c = 64 * wv + lane;
    float acc[SPB4];
    float cb = c2[c];
#pragma unroll
    for (int s = 0; s < SPB4; ++s) acc[s] = cb;
    const float* wp = V2 + c;
#pragma unroll 4
    for (int m = 0; m < 64; ++m) {
      int k0 = 4 * m;
      float w0 = wp[(size_t)(k0 + 0) * 256];
      float w1 = wp[(size_t)(k0 + 1) * 256];
      float w2 = wp[(size_t)(k0 + 2) * 256];
      float w3 = wp[(size_t)(k0 + 3) * 256];
#pragma unroll
      for (int s = 0; s < SPB4; ++s) {
        float4 x = *(float4*)&sA[s * 256 + k0];
        acc[s] += x.x * w0 + x.y * w1 + x.z * w2 + x.w * w3;
      }
    }
#pragma unroll
    for (int s = 0; s < SPB4; ++s) sB[s * 256 + c] = siluf(acc[s]);
  }
  __syncthreads();
  {
    float acc[SPB4] = {};
    const int kb = 64 * wv;
#pragma unroll 4
    for (int m = 0; m < 16; ++m) {
      int k0 = kb + 4 * m;
      float w0 = V3[(k0 + 0) * 64 + lane];
      float w1 = V3[(k0 + 1) * 64 + lane];
      float w2 = V3[(k0 + 2) * 64 + lane];
      float w3 = V3[(k0 + 3) * 64 + lane];
#pragma unroll
      for (int s = 0; s < SPB4; ++s) {
        float4 x = *(float4*)&sB[s * 256 + k0];
        acc[s] += x.x * w0 + x.y * w1 + x.z * w2 + x.w * w3;
      }
    }
#pragma unroll
    for (int s = 0; s < SPB4; ++s) sP[wv * 256 + s * 64 + lane] = acc[s];
  }
  __syncthreads();
  {
    int b = bbase + wv;
    float blv = c3[lane] + sP[wv * 64 + lane] + sP[256 + wv * 64 + lane]
              + sP[512 + wv * 64 + lane] + sP[768 + wv * 64 + lane];
    float eb = __expf(blv);
    float Zb = waveSum(eb);
    float u = ub[(size_t)b * 64 + lane];
    float g = -logf(-logf(fmaxf(u, 1e-10f)));
    float lp = selectAndPL(blv, eb, Zb, g, out + (size_t)b * 128 + 64, lane,
                           sValsRow, sSelERow, nullptr);
    if (lane == 0)
      out[(size_t)8192 * 128 + b] = sLpA[wv] + lp;
  }
}

extern "C" void kernel_launch(void* const* d_in, const int* in_sizes, int n_in,
                              void* d_out, int out_size, void* d_ws, size_t ws_size,
                              hipStream_t stream) {
  const float* ua   = (const float*)d_in[0];
  const float* ub   = (const float*)d_in[1];
  const float* alog = (const float*)d_in[2];
  const float* W1   = (const float*)d_in[3];
  const float* b1   = (const float*)d_in[4];
  const float* W2   = (const float*)d_in[5];
  const float* b2   = (const float*)d_in[6];
  const float* V1   = (const float*)d_in[7];
  const float* c1   = (const float*)d_in[8];
  const float* V2   = (const float*)d_in[9];
  const float* c2   = (const float*)d_in[10];
  const float* V3   = (const float*)d_in[11];
  const float* c3   = (const float*)d_in[12];
  float* out = (float*)d_out;

  if (ws_size >= (size_t)WS_USHORTS * 2) {
    unsigned short* wt = (unsigned short*)d_ws;
    pcf_prep<<<dim3(52), dim3(256), 0, stream>>>(W2, V1, V2, V3, wt);
    pcf_mfma<<<dim3(8192 / SPB), dim3(NTH), 0, stream>>>(
        ua, ub, alog, W1, b1, b2, c1, c2, c3, wt, out);
  } else {
    pcf_small<<<dim3(8192 / SPB4), dim3(256), 0, stream>>>(
        ua, ub, alog, W1, b1, W2, b2, V1, c1, V2, c2, V3, c3, out);
  }
}